// Round 1
// baseline (656.942 us; speedup 1.0000x reference)
//
#include <hip/hip_runtime.h>
#include <math.h>

// ---- problem constants (match reference) ----
#define NN   100000   // nodes
#define DD   128      // in_channels
#define EE   600000   // edges
#define EAD  16       // edge_attr dim
#define BB   50       // graphs
#define NPG  2000     // nodes per graph
#define KK   1000     // kept per graph
#define NKEEP (BB*KK) // 50000

// output layout (floats, concatenated in return order)
// out_x:   [0,           6,400,000)
// oei:     [6,400,000,   7,600,000)   (2 x E)
// oea:     [7,600,000,  17,200,000)   (E x 16)
// obatch:  [17,200,000, 17,250,000)
// emask:   [17,250,000, 17,850,000)
#define OFF_OEI    6400000
#define OFF_OEA    7600000
#define OFF_OBATCH 17200000
#define OFF_EMASK  17250000

#define NRED 240  // reduction blocks

// ============ K1: edge MLP -> ew, deg_w, deg_c ============
__global__ __launch_bounds__(256) void k_edge_mlp(
    const float* __restrict__ edge_attr, const int* __restrict__ src,
    const float* __restrict__ We1, const float* __restrict__ be1,
    const float* __restrict__ We2, const float* __restrict__ be2,
    float* __restrict__ ew, float* __restrict__ deg_w, float* __restrict__ deg_c)
{
    int e = blockIdx.x * 256 + threadIdx.x;
    if (e >= EE) return;
    const float4* ap = (const float4*)(edge_attr + (size_t)e * EAD);
    float4 a0 = ap[0], a1 = ap[1], a2 = ap[2], a3 = ap[3];
    float ea[16] = {a0.x,a0.y,a0.z,a0.w, a1.x,a1.y,a1.z,a1.w,
                    a2.x,a2.y,a2.z,a2.w, a3.x,a3.y,a3.z,a3.w};
    float acc = be2[0];
    for (int j = 0; j < DD; j++) {
        float h = be1[j];
        #pragma unroll
        for (int k = 0; k < 16; k++) h += ea[k] * We1[k*DD + j];
        acc += fmaxf(h, 0.f) * We2[j];
    }
    // stable softplus + eps
    float sp = fmaxf(acc, 0.f) + log1pf(expf(-fabsf(acc)));
    float w = sp + 1e-6f;
    ew[e] = w;
    int s = src[e];
    atomicAdd(&deg_w[s], w);
    atomicAdd(&deg_c[s], 1.0f);
}

// ============ K2: dis = deg_w^-0.5 ============
__global__ __launch_bounds__(256) void k_dis(const float* __restrict__ deg_w,
                                             float* __restrict__ dis)
{
    int n = blockIdx.x * 256 + threadIdx.x;
    if (n >= NN) return;
    float d = deg_w[n];
    dis[n] = d > 0.f ? 1.f / sqrtf(d) : 0.f;
}

// ============ K3: diffusion scatter x_diff[src] += x[dst]*norm ============
__global__ __launch_bounds__(256) void k_diffuse(
    const int* __restrict__ src, const int* __restrict__ dst,
    const float* __restrict__ ew, const float* __restrict__ dis,
    const float* __restrict__ x, float* __restrict__ x_diff)
{
    long long t = (long long)blockIdx.x * 256 + threadIdx.x;
    int e = (int)(t >> 7);
    int d = (int)(t & 127);
    if (e >= EE) return;
    int s = src[e], dd = dst[e];
    float nrm = dis[s] * ew[e] * dis[dd];
    atomicAdd(&x_diff[(size_t)s * DD + d], x[(size_t)dd * DD + d] * nrm);
}

// ============ K4: per-node feat MLP + cosine + log-degree ============
__global__ __launch_bounds__(256) void k_node(
    const float* __restrict__ x, const float* __restrict__ x_diff,
    const float* __restrict__ W1, const float* __restrict__ b1,
    const float* __restrict__ W2, const float* __restrict__ b2,
    const float* __restrict__ deg_c,
    float* __restrict__ raw0, float* __restrict__ raw1, float* __restrict__ raw2)
{
    __shared__ float xs[32 * DD]; // 16 KB: 32 nodes per block
    int wave = threadIdx.x >> 6, lane = threadIdx.x & 63;
    int nodeBase = blockIdx.x * 32 + wave * 8;

    // cooperative load of this wave's 8 x-rows (1024 floats) into LDS
    const float4* xp = (const float4*)(x + (size_t)nodeBase * DD);
    float4* sp4 = (float4*)(xs + wave * 1024);
    #pragma unroll
    for (int i = 0; i < 4; i++) sp4[lane + 64*i] = xp[lane + 64*i];
    __syncthreads();

    const float* xw = xs + wave * 1024;
    float acc[8], acc2[8];
    float b1a = b1[lane], b1b = b1[lane + 64];
    #pragma unroll
    for (int i = 0; i < 8; i++) { acc[i] = b1a; acc2[i] = b1b; }

    for (int k = 0; k < DD; k += 4) {
        float w1a[4], w1b[4];
        #pragma unroll
        for (int kk = 0; kk < 4; kk++) {
            w1a[kk] = W1[(k+kk)*DD + lane];
            w1b[kk] = W1[(k+kk)*DD + lane + 64];
        }
        #pragma unroll
        for (int i = 0; i < 8; i++) {
            float4 xv = *(const float4*)(xw + i*DD + k);
            acc[i]  += xv.x*w1a[0]; acc[i]  += xv.y*w1a[1];
            acc[i]  += xv.z*w1a[2]; acc[i]  += xv.w*w1a[3];
            acc2[i] += xv.x*w1b[0]; acc2[i] += xv.y*w1b[1];
            acc2[i] += xv.z*w1b[2]; acc2[i] += xv.w*w1b[3];
        }
    }
    float w2a = W2[lane], w2b = W2[lane + 64];
    #pragma unroll
    for (int i = 0; i < 8; i++) {
        float v = fmaxf(acc[i], 0.f) * w2a + fmaxf(acc2[i], 0.f) * w2b;
        #pragma unroll
        for (int off = 32; off; off >>= 1) v += __shfl_xor(v, off, 64);
        if (lane == 0) raw1[nodeBase + i] = v + b2[0];
    }
    // cosine view
    #pragma unroll
    for (int i = 0; i < 8; i++) {
        int n = nodeBase + i;
        float x1 = xw[i*DD + lane], x2 = xw[i*DD + lane + 64];
        float d1 = x_diff[(size_t)n*DD + lane], d2 = x_diff[(size_t)n*DD + lane + 64];
        float dot = x1*d1 + x2*d2;
        float nx  = x1*x1 + x2*x2;
        float nd  = d1*d1 + d2*d2;
        #pragma unroll
        for (int off = 32; off; off >>= 1) {
            dot += __shfl_xor(dot, off, 64);
            nx  += __shfl_xor(nx,  off, 64);
            nd  += __shfl_xor(nd,  off, 64);
        }
        if (lane == 0)
            raw2[n] = dot / ((sqrtf(nx) + 1e-6f) * (sqrtf(nd) + 1e-6f));
    }
    if (lane < 8) {
        int n = nodeBase + lane;
        raw0[n] = logf(deg_c[n] + 1.0f);
    }
}

// ============ K5: block-level f64 partial sums (sum, sumsq) x3 ============
__global__ __launch_bounds__(256) void k_reduce(
    const float* __restrict__ r0, const float* __restrict__ r1,
    const float* __restrict__ r2, double* __restrict__ partials)
{
    __shared__ double sd[256];
    double s[6] = {0,0,0,0,0,0};
    for (int n = blockIdx.x * 256 + threadIdx.x; n < NN; n += 256 * NRED) {
        double v0 = r0[n], v1 = r1[n], v2 = r2[n];
        s[0] += v0; s[1] += v0*v0;
        s[2] += v1; s[3] += v1*v1;
        s[4] += v2; s[5] += v2*v2;
    }
    for (int q = 0; q < 6; q++) {
        sd[threadIdx.x] = s[q];
        __syncthreads();
        for (int off = 128; off; off >>= 1) {
            if (threadIdx.x < off) sd[threadIdx.x] += sd[threadIdx.x + off];
            __syncthreads();
        }
        if (threadIdx.x == 0) partials[blockIdx.x * 6 + q] = sd[0];
        __syncthreads();
    }
}

// ============ K6: final stats -> mean, 1/(std+eps) per view ============
__global__ __launch_bounds__(256) void k_stats(const double* __restrict__ partials,
                                               float* __restrict__ stats)
{
    __shared__ double sd[256];
    __shared__ double sums[6];
    for (int q = 0; q < 6; q++) {
        sd[threadIdx.x] = (threadIdx.x < NRED) ? partials[threadIdx.x * 6 + q] : 0.0;
        __syncthreads();
        for (int off = 128; off; off >>= 1) {
            if (threadIdx.x < off) sd[threadIdx.x] += sd[threadIdx.x + off];
            __syncthreads();
        }
        if (threadIdx.x == 0) sums[q] = sd[0];
        __syncthreads();
    }
    if (threadIdx.x == 0) {
        for (int i = 0; i < 3; i++) {
            double sum = sums[2*i], sq = sums[2*i+1];
            double mean = sum / NN;
            double var = (sq - sum * sum / NN) / (NN - 1);
            double sdv = sqrt(var > 0 ? var : 0);
            stats[2*i]   = (float)mean;
            stats[2*i+1] = (float)(1.0 / (sdv + 1e-6));
        }
    }
}

// ============ K7: score = sigmoid(z @ vw) ============
__global__ __launch_bounds__(256) void k_score(
    const float* __restrict__ r0, const float* __restrict__ r1,
    const float* __restrict__ r2, const float* __restrict__ stats,
    const float* __restrict__ vw, float* __restrict__ score)
{
    int n = blockIdx.x * 256 + threadIdx.x;
    if (n >= NN) return;
    float z0 = (r0[n] - stats[0]) * stats[1];
    float z1 = (r1[n] - stats[2]) * stats[3];
    float z2 = (r2[n] - stats[4]) * stats[5];
    float r = z0 * vw[0] + z1 * vw[1] + z2 * vw[2];
    score[n] = 1.f / (1.f + expf(-r));
}

// ============ K8: per-graph top-K via bitonic sort of 2048 keys ============
__global__ __launch_bounds__(1024) void k_topk(
    const float* __restrict__ score, int* __restrict__ keep,
    int* __restrict__ new_id, float* __restrict__ obatch)
{
    __shared__ unsigned long long keys[2048];
    int b = blockIdx.x;
    unsigned t = threadIdx.x;
    for (unsigned i = t; i < 2048; i += 1024) {
        unsigned long long kk = 0ull;
        if (i < NPG) {
            float sc = score[b * NPG + i];
            // descending score, ties -> lower index first
            kk = ((unsigned long long)__float_as_uint(sc) << 32)
               | (unsigned long long)(0xFFFFFFFFu - i);
        }
        keys[i] = kk;
    }
    __syncthreads();
    for (unsigned k = 2; k <= 2048; k <<= 1) {
        for (unsigned j = k >> 1; j > 0; j >>= 1) {
            unsigned i = ((t & ~(j - 1)) << 1) | (t & (j - 1));
            unsigned p = i | j;
            unsigned long long a = keys[i], c = keys[p];
            bool up = ((i & k) == 0);
            if ((a < c) == up) { keys[i] = c; keys[p] = a; } // descending
            __syncthreads();
        }
    }
    if (t < KK) {
        unsigned long long kk = keys[t];
        unsigned li = 0xFFFFFFFFu - (unsigned)(kk & 0xFFFFFFFFu);
        int node = b * NPG + (int)li;
        int j = b * KK + (int)t;
        keep[j] = node;
        new_id[node] = j;
        obatch[j] = (float)b;
    }
}

// ============ K9: out_x = x[keep] * score[keep] ============
__global__ __launch_bounds__(128) void k_outx(
    const float* __restrict__ x, const float* __restrict__ score,
    const int* __restrict__ keep, float* __restrict__ out_x)
{
    int j = blockIdx.x;
    int node = keep[j];
    float s = score[node];
    out_x[(size_t)j * DD + threadIdx.x] = x[(size_t)node * DD + threadIdx.x] * s;
}

// ============ K10a: edge mask + new edge_index ============
__global__ __launch_bounds__(256) void k_edges(
    const int* __restrict__ src, const int* __restrict__ dst,
    const int* __restrict__ new_id, float* __restrict__ oei,
    float* __restrict__ emask)
{
    int e = blockIdx.x * 256 + threadIdx.x;
    if (e >= EE) return;
    int ns = new_id[src[e]], nd = new_id[dst[e]];
    bool m = (ns >= 0) && (nd >= 0);
    oei[e]      = m ? (float)ns : 0.f;
    oei[EE + e] = m ? (float)nd : 0.f;
    emask[e]    = m ? 1.f : 0.f;
}

// ============ K10b: masked edge_attr copy (float4) ============
__global__ __launch_bounds__(256) void k_attr(
    const float* __restrict__ edge_attr, const float* __restrict__ emask,
    float* __restrict__ oea)
{
    int idx = blockIdx.x * 256 + threadIdx.x; // over EE*4 float4s
    if (idx >= EE * 4) return;
    int e = idx >> 2;
    float m = emask[e];
    float4 v = ((const float4*)edge_attr)[idx];
    float4 o; o.x = v.x*m; o.y = v.y*m; o.z = v.z*m; o.w = v.w*m;
    ((float4*)oea)[idx] = o;
}

extern "C" void kernel_launch(void* const* d_in, const int* in_sizes, int n_in,
                              void* d_out, int out_size, void* d_ws, size_t ws_size,
                              hipStream_t stream) {
    const float* x         = (const float*)d_in[0];
    const int*   edge_idx  = (const int*)d_in[1];
    const float* edge_attr = (const float*)d_in[2];
    // d_in[3] = batch (unused; graphs are contiguous equal blocks)
    const float* W1  = (const float*)d_in[4];
    const float* b1  = (const float*)d_in[5];
    const float* W2  = (const float*)d_in[6];
    const float* b2  = (const float*)d_in[7];
    const float* We1 = (const float*)d_in[8];
    const float* be1 = (const float*)d_in[9];
    const float* We2 = (const float*)d_in[10];
    const float* be2 = (const float*)d_in[11];
    const float* vw  = (const float*)d_in[12];

    const int* src = edge_idx;
    const int* dst = edge_idx + EE;

    float* out    = (float*)d_out;
    float* out_x  = out;
    float* oei    = out + OFF_OEI;
    float* oea    = out + OFF_OEA;
    float* obatch = out + OFF_OBATCH;
    float* emask  = out + OFF_EMASK;

    // x_diff (51.2 MB) lives in d_out[0 .. 12.8M floats) — dead before any
    // output writer (k_outx/k_edges/k_attr/k_topk-obatch) runs.
    float* x_diff = out;

    // workspace layout (floats) — ~5.9 MB total
    float* ws     = (float*)d_ws;
    float* ew     = ws;                     // 600000
    float* deg_w  = ws + 600000;            // 100000
    float* deg_c  = ws + 700000;            // 100000
    float* dis    = ws + 800000;            // 100000
    float* score  = ws + 900000;            // 100000
    float* raw0   = ws + 1000000;           // 100000
    float* raw1   = ws + 1100000;           // 100000
    float* raw2   = ws + 1200000;           // 100000
    int*   keep   = (int*)(ws + 1300000);   // 50000
    int*   new_id = (int*)(ws + 1350000);   // 100000
    double* partials = (double*)(ws + 1450000); // NRED*6 doubles (byte off 5.8M, 8B aligned)
    float* stats  = ws + 1450000 + 2 * 6 * NRED; // 6 floats

    hipMemsetAsync(deg_w, 0, NN * sizeof(float), stream);
    hipMemsetAsync(deg_c, 0, NN * sizeof(float), stream);
    hipMemsetAsync(new_id, 0xFF, NN * sizeof(int), stream); // -1
    hipMemsetAsync(x_diff, 0, (size_t)NN * DD * sizeof(float), stream);

    k_edge_mlp<<<(EE + 255) / 256, 256, 0, stream>>>(edge_attr, src, We1, be1, We2, be2,
                                                     ew, deg_w, deg_c);
    k_dis<<<(NN + 255) / 256, 256, 0, stream>>>(deg_w, dis);
    k_diffuse<<<(EE * 128) / 256, 256, 0, stream>>>(src, dst, ew, dis, x, x_diff);
    k_node<<<NN / 32, 256, 0, stream>>>(x, x_diff, W1, b1, W2, b2, deg_c,
                                        raw0, raw1, raw2);
    k_reduce<<<NRED, 256, 0, stream>>>(raw0, raw1, raw2, partials);
    k_stats<<<1, 256, 0, stream>>>(partials, stats);
    k_score<<<(NN + 255) / 256, 256, 0, stream>>>(raw0, raw1, raw2, stats, vw, score);
    k_topk<<<BB, 1024, 0, stream>>>(score, keep, new_id, obatch);
    k_outx<<<NKEEP, 128, 0, stream>>>(x, score, keep, out_x);
    k_edges<<<(EE + 255) / 256, 256, 0, stream>>>(src, dst, new_id, oei, emask);
    k_attr<<<(EE * 4 + 255) / 256, 256, 0, stream>>>(edge_attr, emask, oea);
}

// Round 2
// 511.148 us; speedup vs baseline: 1.2852x; 1.2852x over previous
//
#include <hip/hip_runtime.h>
#include <math.h>

// ---- problem constants (match reference) ----
#define NN   100000   // nodes
#define DD   128      // in_channels
#define EE   600000   // edges
#define EAD  16       // edge_attr dim
#define BB   50       // graphs
#define NPG  2000     // nodes per graph
#define KK   1000     // kept per graph
#define NKEEP (BB*KK) // 50000

// output layout (floats, concatenated in return order)
#define OFF_OEI    6400000
#define OFF_OEA    7600000
#define OFF_OBATCH 17200000
#define OFF_EMASK  17250000

// scratch inside d_out (all dead before any output writer runs)
// x_diff:   [0,          12,800,000)
// csr_dst:  [12,800,000, 13,400,000)  int
// csr_w:    [13,400,000, 14,000,000)  float
// rowstart: [14,000,000, 14,100,000)  int
// cur:      [14,100,000, 14,200,000)  int
// scanned:  [14,200,000, 14,300,000)  int (exclusive in-block scan)
// blockoff: [14,300,000, 14,300,256)  int
#define NRED 240  // reduction blocks
#define SCAN_NB 98 // ceil(100000/1024)

// ============ K1: edge MLP -> ew, deg_w, deg_c ============
__global__ __launch_bounds__(256) void k_edge_mlp(
    const float* __restrict__ edge_attr, const int* __restrict__ src,
    const float* __restrict__ We1, const float* __restrict__ be1,
    const float* __restrict__ We2, const float* __restrict__ be2,
    float* __restrict__ ew, float* __restrict__ deg_w, float* __restrict__ deg_c)
{
    int e = blockIdx.x * 256 + threadIdx.x;
    if (e >= EE) return;
    const float4* ap = (const float4*)(edge_attr + (size_t)e * EAD);
    float4 a0 = ap[0], a1 = ap[1], a2 = ap[2], a3 = ap[3];
    float ea[16] = {a0.x,a0.y,a0.z,a0.w, a1.x,a1.y,a1.z,a1.w,
                    a2.x,a2.y,a2.z,a2.w, a3.x,a3.y,a3.z,a3.w};
    float acc = be2[0];
    for (int j = 0; j < DD; j++) {
        float h = be1[j];
        #pragma unroll
        for (int k = 0; k < 16; k++) h += ea[k] * We1[k*DD + j];
        acc += fmaxf(h, 0.f) * We2[j];
    }
    float sp = fmaxf(acc, 0.f) + log1pf(expf(-fabsf(acc)));
    float w = sp + 1e-6f;
    ew[e] = w;
    int s = src[e];
    atomicAdd(&deg_w[s], w);
    atomicAdd(&deg_c[s], 1.0f);
}

// ============ K2: dis = deg_w^-0.5 ============
__global__ __launch_bounds__(256) void k_dis(const float* __restrict__ deg_w,
                                             float* __restrict__ dis)
{
    int n = blockIdx.x * 256 + threadIdx.x;
    if (n >= NN) return;
    float d = deg_w[n];
    dis[n] = d > 0.f ? 1.f / sqrtf(d) : 0.f;
}

// ============ K3a: per-1024-block exclusive scan of degree counts ============
__global__ __launch_bounds__(1024) void k_scan_block(
    const float* __restrict__ deg_c, int* __restrict__ scanned,
    int* __restrict__ blocksums)
{
    __shared__ int s[1024];
    int i = blockIdx.x * 1024 + threadIdx.x;
    int c = (i < NN) ? (int)deg_c[i] : 0;
    s[threadIdx.x] = c;
    __syncthreads();
    for (int off = 1; off < 1024; off <<= 1) {
        int v = (threadIdx.x >= off) ? s[threadIdx.x - off] : 0;
        __syncthreads();
        s[threadIdx.x] += v;
        __syncthreads();
    }
    if (i < NN) scanned[i] = s[threadIdx.x] - c; // exclusive
    if (threadIdx.x == 1023) blocksums[blockIdx.x] = s[1023];
}

// ============ K3b: scan the block sums (one block) ============
__global__ __launch_bounds__(128) void k_scan_top(int* __restrict__ blocksums)
{
    __shared__ int s[128];
    int c = (threadIdx.x < SCAN_NB) ? blocksums[threadIdx.x] : 0;
    s[threadIdx.x] = c;
    __syncthreads();
    for (int off = 1; off < 128; off <<= 1) {
        int v = (threadIdx.x >= off) ? s[threadIdx.x - off] : 0;
        __syncthreads();
        s[threadIdx.x] += v;
        __syncthreads();
    }
    if (threadIdx.x < SCAN_NB) blocksums[threadIdx.x] = s[threadIdx.x] - c; // exclusive
}

// ============ K3c: rowstart / cursor init ============
__global__ __launch_bounds__(256) void k_cursor(
    const int* __restrict__ scanned, const int* __restrict__ blocksums,
    int* __restrict__ rowstart, int* __restrict__ cur)
{
    int n = blockIdx.x * 256 + threadIdx.x;
    if (n >= NN) return;
    int st = scanned[n] + blocksums[n >> 10];
    rowstart[n] = st;
    cur[n] = st;
}

// ============ K3d: scatter edges into CSR buckets (dst + norm) ============
__global__ __launch_bounds__(256) void k_scatter(
    const int* __restrict__ src, const int* __restrict__ dst,
    const float* __restrict__ ew, const float* __restrict__ dis,
    int* __restrict__ cur, int* __restrict__ csr_dst, float* __restrict__ csr_w)
{
    int e = blockIdx.x * 256 + threadIdx.x;
    if (e >= EE) return;
    int s = src[e], d = dst[e];
    float w = dis[s] * ew[e] * dis[d];
    int pos = atomicAdd(&cur[s], 1);
    csr_dst[pos] = d;
    csr_w[pos] = w;
}

// ============ K3e: gather diffusion — one wave per node, no atomics ============
__global__ __launch_bounds__(256) void k_gather(
    const int* __restrict__ rowstart, const float* __restrict__ deg_c,
    const int* __restrict__ csr_dst, const float* __restrict__ csr_w,
    const float* __restrict__ x, float* __restrict__ x_diff)
{
    int wid = (blockIdx.x * 256 + threadIdx.x) >> 6; // node id (wave-uniform)
    int lane = threadIdx.x & 63;
    if (wid >= NN) return;
    int start = rowstart[wid];
    int end = start + (int)deg_c[wid];
    const float2* xp = (const float2*)x;
    float2 acc = {0.f, 0.f};
    for (int e = start; e < end; e++) {
        int d = csr_dst[e];
        float w = csr_w[e];
        float2 xv = xp[(size_t)d * 64 + lane];
        acc.x += xv.x * w;
        acc.y += xv.y * w;
    }
    ((float2*)x_diff)[(size_t)wid * 64 + lane] = acc;
}

// ============ K4: per-node feat MLP + cosine + log-degree ============
__global__ __launch_bounds__(256) void k_node(
    const float* __restrict__ x, const float* __restrict__ x_diff,
    const float* __restrict__ W1, const float* __restrict__ b1,
    const float* __restrict__ W2, const float* __restrict__ b2,
    const float* __restrict__ deg_c,
    float* __restrict__ raw0, float* __restrict__ raw1, float* __restrict__ raw2)
{
    __shared__ float xs[32 * DD]; // 16 KB: 32 nodes per block
    int wave = threadIdx.x >> 6, lane = threadIdx.x & 63;
    int nodeBase = blockIdx.x * 32 + wave * 8;

    const float4* xp = (const float4*)(x + (size_t)nodeBase * DD);
    float4* sp4 = (float4*)(xs + wave * 1024);
    #pragma unroll
    for (int i = 0; i < 4; i++) sp4[lane + 64*i] = xp[lane + 64*i];
    __syncthreads();

    const float* xw = xs + wave * 1024;
    float acc[8], acc2[8];
    float b1a = b1[lane], b1b = b1[lane + 64];
    #pragma unroll
    for (int i = 0; i < 8; i++) { acc[i] = b1a; acc2[i] = b1b; }

    for (int k = 0; k < DD; k += 4) {
        float w1a[4], w1b[4];
        #pragma unroll
        for (int kk = 0; kk < 4; kk++) {
            w1a[kk] = W1[(k+kk)*DD + lane];
            w1b[kk] = W1[(k+kk)*DD + lane + 64];
        }
        #pragma unroll
        for (int i = 0; i < 8; i++) {
            float4 xv = *(const float4*)(xw + i*DD + k);
            acc[i]  += xv.x*w1a[0]; acc[i]  += xv.y*w1a[1];
            acc[i]  += xv.z*w1a[2]; acc[i]  += xv.w*w1a[3];
            acc2[i] += xv.x*w1b[0]; acc2[i] += xv.y*w1b[1];
            acc2[i] += xv.z*w1b[2]; acc2[i] += xv.w*w1b[3];
        }
    }
    float w2a = W2[lane], w2b = W2[lane + 64];
    #pragma unroll
    for (int i = 0; i < 8; i++) {
        float v = fmaxf(acc[i], 0.f) * w2a + fmaxf(acc2[i], 0.f) * w2b;
        #pragma unroll
        for (int off = 32; off; off >>= 1) v += __shfl_xor(v, off, 64);
        if (lane == 0) raw1[nodeBase + i] = v + b2[0];
    }
    #pragma unroll
    for (int i = 0; i < 8; i++) {
        int n = nodeBase + i;
        float x1 = xw[i*DD + lane], x2 = xw[i*DD + lane + 64];
        float d1 = x_diff[(size_t)n*DD + lane], d2 = x_diff[(size_t)n*DD + lane + 64];
        float dot = x1*d1 + x2*d2;
        float nx  = x1*x1 + x2*x2;
        float nd  = d1*d1 + d2*d2;
        #pragma unroll
        for (int off = 32; off; off >>= 1) {
            dot += __shfl_xor(dot, off, 64);
            nx  += __shfl_xor(nx,  off, 64);
            nd  += __shfl_xor(nd,  off, 64);
        }
        if (lane == 0)
            raw2[n] = dot / ((sqrtf(nx) + 1e-6f) * (sqrtf(nd) + 1e-6f));
    }
    if (lane < 8) {
        int n = nodeBase + lane;
        raw0[n] = logf(deg_c[n] + 1.0f);
    }
}

// ============ K5: block-level f64 partial sums (sum, sumsq) x3 ============
__global__ __launch_bounds__(256) void k_reduce(
    const float* __restrict__ r0, const float* __restrict__ r1,
    const float* __restrict__ r2, double* __restrict__ partials)
{
    __shared__ double sd[256];
    double s[6] = {0,0,0,0,0,0};
    for (int n = blockIdx.x * 256 + threadIdx.x; n < NN; n += 256 * NRED) {
        double v0 = r0[n], v1 = r1[n], v2 = r2[n];
        s[0] += v0; s[1] += v0*v0;
        s[2] += v1; s[3] += v1*v1;
        s[4] += v2; s[5] += v2*v2;
    }
    for (int q = 0; q < 6; q++) {
        sd[threadIdx.x] = s[q];
        __syncthreads();
        for (int off = 128; off; off >>= 1) {
            if (threadIdx.x < off) sd[threadIdx.x] += sd[threadIdx.x + off];
            __syncthreads();
        }
        if (threadIdx.x == 0) partials[blockIdx.x * 6 + q] = sd[0];
        __syncthreads();
    }
}

// ============ K6: final stats -> mean, 1/(std+eps) per view ============
__global__ __launch_bounds__(256) void k_stats(const double* __restrict__ partials,
                                               float* __restrict__ stats)
{
    __shared__ double sd[256];
    __shared__ double sums[6];
    for (int q = 0; q < 6; q++) {
        sd[threadIdx.x] = (threadIdx.x < NRED) ? partials[threadIdx.x * 6 + q] : 0.0;
        __syncthreads();
        for (int off = 128; off; off >>= 1) {
            if (threadIdx.x < off) sd[threadIdx.x] += sd[threadIdx.x + off];
            __syncthreads();
        }
        if (threadIdx.x == 0) sums[q] = sd[0];
        __syncthreads();
    }
    if (threadIdx.x == 0) {
        for (int i = 0; i < 3; i++) {
            double sum = sums[2*i], sq = sums[2*i+1];
            double mean = sum / NN;
            double var = (sq - sum * sum / NN) / (NN - 1);
            double sdv = sqrt(var > 0 ? var : 0);
            stats[2*i]   = (float)mean;
            stats[2*i+1] = (float)(1.0 / (sdv + 1e-6));
        }
    }
}

// ============ K7: score = sigmoid(z @ vw) ============
__global__ __launch_bounds__(256) void k_score(
    const float* __restrict__ r0, const float* __restrict__ r1,
    const float* __restrict__ r2, const float* __restrict__ stats,
    const float* __restrict__ vw, float* __restrict__ score)
{
    int n = blockIdx.x * 256 + threadIdx.x;
    if (n >= NN) return;
    float z0 = (r0[n] - stats[0]) * stats[1];
    float z1 = (r1[n] - stats[2]) * stats[3];
    float z2 = (r2[n] - stats[4]) * stats[5];
    float r = z0 * vw[0] + z1 * vw[1] + z2 * vw[2];
    score[n] = 1.f / (1.f + expf(-r));
}

// ============ K8: per-graph top-K via bitonic sort of 2048 keys ============
__global__ __launch_bounds__(1024) void k_topk(
    const float* __restrict__ score, int* __restrict__ keep,
    int* __restrict__ new_id, float* __restrict__ obatch)
{
    __shared__ unsigned long long keys[2048];
    int b = blockIdx.x;
    unsigned t = threadIdx.x;
    for (unsigned i = t; i < 2048; i += 1024) {
        unsigned long long kk = 0ull;
        if (i < NPG) {
            float sc = score[b * NPG + i];
            kk = ((unsigned long long)__float_as_uint(sc) << 32)
               | (unsigned long long)(0xFFFFFFFFu - i);
        }
        keys[i] = kk;
    }
    __syncthreads();
    for (unsigned k = 2; k <= 2048; k <<= 1) {
        for (unsigned j = k >> 1; j > 0; j >>= 1) {
            unsigned i = ((t & ~(j - 1)) << 1) | (t & (j - 1));
            unsigned p = i | j;
            unsigned long long a = keys[i], c = keys[p];
            bool up = ((i & k) == 0);
            if ((a < c) == up) { keys[i] = c; keys[p] = a; }
            __syncthreads();
        }
    }
    if (t < KK) {
        unsigned long long kk = keys[t];
        unsigned li = 0xFFFFFFFFu - (unsigned)(kk & 0xFFFFFFFFu);
        int node = b * NPG + (int)li;
        int j = b * KK + (int)t;
        keep[j] = node;
        new_id[node] = j;
        obatch[j] = (float)b;
    }
}

// ============ K9: out_x = x[keep] * score[keep] ============
__global__ __launch_bounds__(128) void k_outx(
    const float* __restrict__ x, const float* __restrict__ score,
    const int* __restrict__ keep, float* __restrict__ out_x)
{
    int j = blockIdx.x;
    int node = keep[j];
    float s = score[node];
    out_x[(size_t)j * DD + threadIdx.x] = x[(size_t)node * DD + threadIdx.x] * s;
}

// ============ K10a: edge mask + new edge_index ============
__global__ __launch_bounds__(256) void k_edges(
    const int* __restrict__ src, const int* __restrict__ dst,
    const int* __restrict__ new_id, float* __restrict__ oei,
    float* __restrict__ emask)
{
    int e = blockIdx.x * 256 + threadIdx.x;
    if (e >= EE) return;
    int ns = new_id[src[e]], nd = new_id[dst[e]];
    bool m = (ns >= 0) && (nd >= 0);
    oei[e]      = m ? (float)ns : 0.f;
    oei[EE + e] = m ? (float)nd : 0.f;
    emask[e]    = m ? 1.f : 0.f;
}

// ============ K10b: masked edge_attr copy (float4) ============
__global__ __launch_bounds__(256) void k_attr(
    const float* __restrict__ edge_attr, const float* __restrict__ emask,
    float* __restrict__ oea)
{
    int idx = blockIdx.x * 256 + threadIdx.x;
    if (idx >= EE * 4) return;
    int e = idx >> 2;
    float m = emask[e];
    float4 v = ((const float4*)edge_attr)[idx];
    float4 o; o.x = v.x*m; o.y = v.y*m; o.z = v.z*m; o.w = v.w*m;
    ((float4*)oea)[idx] = o;
}

extern "C" void kernel_launch(void* const* d_in, const int* in_sizes, int n_in,
                              void* d_out, int out_size, void* d_ws, size_t ws_size,
                              hipStream_t stream) {
    const float* x         = (const float*)d_in[0];
    const int*   edge_idx  = (const int*)d_in[1];
    const float* edge_attr = (const float*)d_in[2];
    const float* W1  = (const float*)d_in[4];
    const float* b1  = (const float*)d_in[5];
    const float* W2  = (const float*)d_in[6];
    const float* b2  = (const float*)d_in[7];
    const float* We1 = (const float*)d_in[8];
    const float* be1 = (const float*)d_in[9];
    const float* We2 = (const float*)d_in[10];
    const float* be2 = (const float*)d_in[11];
    const float* vw  = (const float*)d_in[12];

    const int* src = edge_idx;
    const int* dst = edge_idx + EE;

    float* out    = (float*)d_out;
    float* out_x  = out;
    float* oei    = out + OFF_OEI;
    float* oea    = out + OFF_OEA;
    float* obatch = out + OFF_OBATCH;
    float* emask  = out + OFF_EMASK;

    // scratch inside d_out (dead before any output writer runs)
    float* x_diff    = out;                       // 12.8M floats
    int*   csr_dst   = (int*)(out + 12800000);    // 600k
    float* csr_w     = out + 13400000;            // 600k
    int*   rowstart  = (int*)(out + 14000000);    // 100k
    int*   cur       = (int*)(out + 14100000);    // 100k
    int*   scanned   = (int*)(out + 14200000);    // 100k
    int*   blocksums = (int*)(out + 14300000);    // 256

    // workspace layout (floats) — ~5.9 MB total
    float* ws     = (float*)d_ws;
    float* ew     = ws;                     // 600000
    float* deg_w  = ws + 600000;            // 100000
    float* deg_c  = ws + 700000;            // 100000
    float* dis    = ws + 800000;            // 100000
    float* score  = ws + 900000;            // 100000
    float* raw0   = ws + 1000000;           // 100000
    float* raw1   = ws + 1100000;           // 100000
    float* raw2   = ws + 1200000;           // 100000
    int*   keep   = (int*)(ws + 1300000);   // 50000
    int*   new_id = (int*)(ws + 1350000);   // 100000
    double* partials = (double*)(ws + 1450000); // NRED*6 doubles
    float* stats  = ws + 1450000 + 2 * 6 * NRED; // 6 floats

    hipMemsetAsync(deg_w, 0, NN * sizeof(float), stream);
    hipMemsetAsync(deg_c, 0, NN * sizeof(float), stream);
    hipMemsetAsync(new_id, 0xFF, NN * sizeof(int), stream); // -1

    k_edge_mlp<<<(EE + 255) / 256, 256, 0, stream>>>(edge_attr, src, We1, be1, We2, be2,
                                                     ew, deg_w, deg_c);
    k_dis<<<(NN + 255) / 256, 256, 0, stream>>>(deg_w, dis);
    // CSR build
    k_scan_block<<<SCAN_NB, 1024, 0, stream>>>(deg_c, scanned, blocksums);
    k_scan_top<<<1, 128, 0, stream>>>(blocksums);
    k_cursor<<<(NN + 255) / 256, 256, 0, stream>>>(scanned, blocksums, rowstart, cur);
    k_scatter<<<(EE + 255) / 256, 256, 0, stream>>>(src, dst, ew, dis, cur, csr_dst, csr_w);
    // gather diffusion (no atomics, no memset needed: every row fully written)
    k_gather<<<(NN * 64 + 255) / 256, 256, 0, stream>>>(rowstart, deg_c, csr_dst, csr_w,
                                                        x, x_diff);
    k_node<<<NN / 32, 256, 0, stream>>>(x, x_diff, W1, b1, W2, b2, deg_c,
                                        raw0, raw1, raw2);
    k_reduce<<<NRED, 256, 0, stream>>>(raw0, raw1, raw2, partials);
    k_stats<<<1, 256, 0, stream>>>(partials, stats);
    k_score<<<(NN + 255) / 256, 256, 0, stream>>>(raw0, raw1, raw2, stats, vw, score);
    k_topk<<<BB, 1024, 0, stream>>>(score, keep, new_id, obatch);
    k_outx<<<NKEEP, 128, 0, stream>>>(x, score, keep, out_x);
    k_edges<<<(EE + 255) / 256, 256, 0, stream>>>(src, dst, new_id, oei, emask);
    k_attr<<<(EE * 4 + 255) / 256, 256, 0, stream>>>(edge_attr, emask, oea);
}